// Round 11
// baseline (30.535 us; speedup 1.0000x reference)
//
#include <hip/hip_runtime.h>

// Path signature depth 4, path (N=64, L=512, C=8) fp32. Two kernels.
//
// k1: 256 blocks (n, g 0..3), 4 waves. Wave w computes chunk (g*4+w)'s
//     signature (32 Chen steps, state fully in registers, packed f2 math)
//     and stores it STRAIGHT to ws — no in-block combine, 1 barrier, 4KB LDS.
//     (R10 analysis: the in-block combine's barriers+LDS latency chains at
//     1 wave/SIMD were the cost, not the arithmetic.)
// k2: 256 blocks (n, c-quadrant w4). Combines the 16 chunk sigs via the
//     prefix expansion: 15 TINY L123-only serial products (the only serial
//     part), then one barrier-free L4 accumulation over j=0..15 terms.
//     L123 chain is redundantly computed by all 4 quadrant blocks (identical
//     bits); only w4==0 stores it.
//
// R6 lesson: no atomic+fence cross-block handoff. R7 lesson: cross-wave LDS
// reads need the barrier (prefix products here use distinct output buffers
// and a barrier per product).
//
// ws chunk-sig layout (stride 4744 floats):
//   [0,8) L1, [8,72) L2 flat, [72,648) L3 B-layout (72 + a*72 + b*8 + c),
//   [648,4744) L4 T-layout: float4 #i of k1-lane l at f4-index i*64 + l,
//   where lane l=(a*8+b) f4 #i covers (a, b, c=i>>1, d=(i&1)*4 ..+3).

typedef float f2 __attribute__((ext_vector_type(2)));

#define NB 64
#define LP 512
#define SIG 4680
#define O2 8
#define O3 72
#define WSS 4744         // ws sig stride in floats
#define WL4 162          // f4 offset of L4 region in a ws sig
#define SB 648

#define B3IDX(x, y, z) (72 + (x) * 72 + (y) * 8 + (z))

__device__ __forceinline__ f2 mkf2(float x, float y) { f2 r; r[0] = x; r[1] = y; return r; }

// ---------------------------------------------------------------------------
// k1: 256 blocks x 256 thr. Pure chunk signatures (no combine).
// ---------------------------------------------------------------------------
__global__ __launch_bounds__(256) void k1_sig(const float* __restrict__ path,
                                              float* __restrict__ ws)
{
    __shared__ __align__(16) float zbuf[128 * 8];
    const int tid = threadIdx.x;
    const int n = blockIdx.x >> 2;
    const int g = blockIdx.x & 3;

    {   // stage 128 increments (zero-padded past t=510; exp(0) = identity)
        const int r = tid >> 1, h = tid & 1;
        const int t = g * 128 + r;
        const float4* p4 = (const float4*)path + (size_t)n * (LP * 2);
        float4 z4 = make_float4(0.f, 0.f, 0.f, 0.f);
        if (t < LP - 1) {
            float4 x0 = p4[t * 2 + h];
            float4 x1 = p4[t * 2 + 2 + h];
            z4 = make_float4(x1.x - x0.x, x1.y - x0.y, x1.z - x0.z, x1.w - x0.w);
        }
        ((float4*)zbuf)[tid] = z4;
    }
    __syncthreads();

    const int w = tid >> 6, l = tid & 63;
    const int a = l >> 3, b = l & 7;

    // ---- 32-step chunk signature in registers (packed f2 math) ----
    float s1 = 0.f, s2 = 0.f;
    f2 s3p[4], s4p[32];
    #pragma unroll
    for (int i = 0; i < 4; ++i) s3p[i] = mkf2(0.f, 0.f);
    #pragma unroll
    for (int e = 0; e < 32; ++e) s4p[e] = mkf2(0.f, 0.f);

    const float* zw = zbuf + w * (32 * 8);
    #pragma unroll 4
    for (int s = 0; s < 32; ++s) {
        const float* zs = zw + s * 8;
        f2 zp[4];
        #pragma unroll
        for (int j = 0; j < 4; ++j) zp[j] = ((const f2*)zs)[j];
        const float za  = zs[a];
        const float zbv = zs[b];
        const float B4 = zbv * (za * (1.f/24.f) + s1 * (1.f/6.f)) + s2 * 0.5f;
        const float G3 = zbv * (za * (1.f/6.f)  + s1 * 0.5f)      + s2;
        f2 Acp[4];
        #pragma unroll
        for (int i = 0; i < 4; ++i) Acp[i] = B4 * zp[i] + s3p[i];
        #pragma unroll
        for (int c = 0; c < 8; ++c) {
            const float Ac = Acp[c >> 1][c & 1];
            #pragma unroll
            for (int j = 0; j < 4; ++j) s4p[c * 4 + j] += Ac * zp[j];
        }
        #pragma unroll
        for (int i = 0; i < 4; ++i) s3p[i] += G3 * zp[i];
        s2 += zbv * (za * 0.5f + s1);
        s1 += za;
    }

    // ---- store chunk sig: B-layout L123 + T-layout L4 (coalesced) ----
    float* dst = ws + (size_t)(n * 16 + g * 4 + w) * WSS;
    if (b == 0) dst[a] = s1;
    dst[O2 + l] = s2;
    *(float4*)&dst[B3IDX(a, b, 0)] = make_float4(s3p[0][0], s3p[0][1], s3p[1][0], s3p[1][1]);
    *(float4*)&dst[B3IDX(a, b, 4)] = make_float4(s3p[2][0], s3p[2][1], s3p[3][0], s3p[3][1]);
    float4* dT = (float4*)dst + WL4;
    #pragma unroll
    for (int i = 0; i < 16; ++i)
        dT[i * 64 + l] = make_float4(s4p[2*i][0], s4p[2*i][1], s4p[2*i+1][0], s4p[2*i+1][1]);
}

// ---------------------------------------------------------------------------
// k2: 256 blocks x 256 thr = (batch n, c-quadrant w4). Prefix-combine 16 sigs.
// ---------------------------------------------------------------------------
__global__ __launch_bounds__(256) void k2_final(const float* __restrict__ ws,
                                                float* __restrict__ out)
{
    // sBuf[0..15] = staged S_m L123 (B-layout); sBuf[15+j] = prefix P_j L123
    // for j=1..15 (P_0 aliases sBuf[0]).  31 * 648 * 4 B = 80.4 KB.
    __shared__ __align__(16) float sBuf[31][SB];

    const int tid = threadIdx.x;
    const int n  = blockIdx.x >> 2;
    const int w4 = blockIdx.x & 3;
    const int a = tid >> 5, b = (tid >> 2) & 7, q = tid & 3;
    const int cc = q >> 1, dh4 = q & 1;
    const int c  = 2 * w4 + cc;
    const int dh = dh4 * 4;
    const int f0 = 2 * tid;
    const int pp = f0 >> 6, qq = (f0 >> 3) & 7, rr = f0 & 7;   // rr even
    const float* base = ws + (size_t)n * 16 * WSS;

    // issue this thread's 16 L4 quadrant float4s first (latency overlaps staging)
    const int ti = (w4 * 4 + cc * 2 + dh4) * 64 + (a * 8 + b);
    f2 b4[16][2];
    #pragma unroll
    for (int m = 0; m < 16; ++m) {
        float4 u = ((const float4*)(base + (size_t)m * WSS))[WL4 + ti];
        b4[m][0] = mkf2(u.x, u.y);
        b4[m][1] = mkf2(u.z, u.w);
    }

    // stage all 16 L123 blocks (162 float4 each), f4-linear (already B-layout)
    for (int e = tid; e < 16 * 162; e += 256) {
        const int m = e / 162, o = e - m * 162;
        ((float4*)sBuf[m])[o] = ((const float4*)(base + (size_t)m * WSS))[o];
    }
    __syncthreads();

    // ---- serial prefix chain (tiny L123-only products), j = 1..15 ----
    #pragma unroll 1
    for (int j = 1; j <= 15; ++j) {
        const float* A = (j == 1) ? sBuf[0] : sBuf[15 + j - 1];
        const float* B = sBuf[j];
        float* P = sBuf[15 + j];
        const float A1p  = A[pp];
        const float A2pq = A[O2 + pp * 8 + qq];
        P[B3IDX(pp, qq, rr)]     = A[B3IDX(pp, qq, rr)]     + B[B3IDX(pp, qq, rr)]
                                 + A2pq * B[rr]     + A1p * B[O2 + qq * 8 + rr];
        P[B3IDX(pp, qq, rr + 1)] = A[B3IDX(pp, qq, rr + 1)] + B[B3IDX(pp, qq, rr + 1)]
                                 + A2pq * B[rr + 1] + A1p * B[O2 + qq * 8 + rr + 1];
        if (tid < 64) P[O2 + tid] = A[O2 + tid] + B[O2 + tid] + A[tid >> 3] * B[tid & 7];
        if (tid < 8)  P[tid] = A[tid] + B[tid];
        __syncthreads();
    }

    // ---- barrier-free L4 accumulation over j-terms ----
    // a4 = S0.L4 + sum_{j=1..15} [ P_{j-1}.L3[abc]*Sj.L1[d] +
    //      P_{j-1}.L2[ab]*Sj.L2[cd] + P_{j-1}.L1[a]*Sj.L3[bcd] + Sj.L4 ]
    f2 a4[2] = { b4[0][0], b4[0][1] };
    #pragma unroll
    for (int j = 1; j <= 15; ++j) {
        const float* Pm = (j == 1) ? sBuf[0] : sBuf[15 + j - 1];
        const float* B  = sBuf[j];
        const float A1  = Pm[a];
        const float A2  = Pm[O2 + a * 8 + b];
        const float A3c = Pm[B3IDX(a, b, c)];
        f2 b1p[2], b2p[2], b3p[2];
        *(float4*)&b1p[0] = *(const float4*)(B + dh);
        *(float4*)&b2p[0] = *(const float4*)(B + O2 + c * 8 + dh);
        *(float4*)&b3p[0] = *(const float4*)(B + B3IDX(b, c, dh));
        #pragma unroll
        for (int t2 = 0; t2 < 2; ++t2)
            a4[t2] += b4[j][t2] + A3c * b1p[t2] + A2 * b2p[t2] + A1 * b3p[t2];
    }

    // ---- store final signature (true flat layout) ----
    float* dst = out + (size_t)n * SIG;
    const float* PF = sBuf[30];   // P_15 = final L123
    if (w4 == 0) {
        if (tid < O3) dst[tid] = PF[tid];
        dst[O3 + f0]     = PF[B3IDX(pp, qq, rr)];
        dst[O3 + f0 + 1] = PF[B3IDX(pp, qq, rr + 1)];
    }
    ((float4*)(dst + 584))[((a * 8 + b) * 8 + c) * 2 + dh4] =
        make_float4(a4[0][0], a4[0][1], a4[1][0], a4[1][1]);
}

extern "C" void kernel_launch(void* const* d_in, const int* in_sizes, int n_in,
                              void* d_out, int out_size, void* d_ws, size_t ws_size,
                              hipStream_t stream) {
    const float* path = (const float*)d_in[0];
    float* out = (float*)d_out;
    float* ws  = (float*)d_ws;   // 64 * 16 * 4744 * 4 B = 19.4 MB used

    k1_sig<<<NB * 4, 256, 0, stream>>>(path, ws);
    k2_final<<<NB * 4, 256, 0, stream>>>(ws, out);
}

// Round 12
// 18.314 us; speedup vs baseline: 1.6673x; 1.6673x over previous
//
#include <hip/hip_runtime.h>

// Path signature depth 4, path (N=64, L=512, C=8) fp32. Two kernels.
//
// k1: 256 blocks (n, g 0..3), 4 waves. Wave w: 32-step chunk signature fully
//     in registers (lane (a,b) owns S4[a][b][*][*] as f2 pairs). Then a TREE
//     combine: level 1 = (S0 x S1) and (S2 x S3) concurrently (L4 in-place in
//     LDS by 128-thread halves, L123 to fresh buffers); level 2 = final
//     product with every element computed by its storing thread. 3 barriers,
//     2 serial products (R10 had 5 barriers / 3 serial products; R11 showed
//     serial-depth dominates cost).
// k2: 256 blocks (n, c-quadrant w4): same 2-level tree on the 4 partials.
//     L123 chain redundantly computed per quadrant block; w4==0 stores it.
//
// R6 lesson: no atomic+fence cross-block handoff (device fence ~0.2us each,
// serialized). R7 lesson: a store may skip the pre-store barrier ONLY if the
// storing thread computed that element itself (true for all stores here).
//
// LDS layouts for L123:
//   A-side (scalar access):  L1 [0,8), L2 [8,72), L3 at 72+(p*8+q)*9+r
//   B-side (float4 access):  L1/L2 flat,           L3 at 72+x*72+y*8+z
// L4 T-layout: float4 #i of lane l at f4-index i*64+l, covering
// (a=l>>3, b=l&7, c=i>>1, d=(i&1)*4..+3).

typedef float f2 __attribute__((ext_vector_type(2)));

#define NB 64
#define LP 512
#define SIG 4680
#define O2 8
#define O3 72
#define O4 584
#define SB 648

#define A3IDX(pq, r) (72 + (pq) * 9 + (r))
#define B3IDX(x, y, z) (72 + (x) * 72 + (y) * 8 + (z))

__device__ __forceinline__ f2 mkf2(float x, float y) { f2 r; r[0] = x; r[1] = y; return r; }

// ---------------------------------------------------------------------------
// k1: 256 blocks x 256 thr. 32-step chunks + in-block TREE combine.
// ---------------------------------------------------------------------------
__global__ __launch_bounds__(256) void k1_sig(const float* __restrict__ path,
                                              float* __restrict__ ws)
{
    __shared__ __align__(16) float zbuf[128 * 8];
    __shared__ __align__(16) float sA0[SB], sB1[SB], sA2[SB], sB3[SB];
    __shared__ __align__(16) float sPA[SB], sPB[SB];
    __shared__ __align__(16) float4 sT[4][1024];

    const int tid = threadIdx.x;
    const int n = blockIdx.x >> 2;
    const int g = blockIdx.x & 3;

    {   // stage 128 increments (zero-padded past t=510; exp(0) = identity)
        const int r = tid >> 1, hh = tid & 1;
        const int t = g * 128 + r;
        const float4* p4 = (const float4*)path + (size_t)n * (LP * 2);
        float4 z4 = make_float4(0.f, 0.f, 0.f, 0.f);
        if (t < LP - 1) {
            float4 x0 = p4[t * 2 + hh];
            float4 x1 = p4[t * 2 + 2 + hh];
            z4 = make_float4(x1.x - x0.x, x1.y - x0.y, x1.z - x0.z, x1.w - x0.w);
        }
        ((float4*)zbuf)[tid] = z4;
    }
    __syncthreads();

    const int w = tid >> 6, l = tid & 63;
    const int a = l >> 3, b = l & 7;
    const int f0 = 2 * tid;

    // ---- 32-step chunk signature in registers (packed f2 math) ----
    float s1 = 0.f, s2 = 0.f;
    f2 s3p[4], s4p[32];
    #pragma unroll
    for (int i = 0; i < 4; ++i) s3p[i] = mkf2(0.f, 0.f);
    #pragma unroll
    for (int e = 0; e < 32; ++e) s4p[e] = mkf2(0.f, 0.f);

    const float* zw = zbuf + w * (32 * 8);
    #pragma unroll 4
    for (int s = 0; s < 32; ++s) {
        const float* zs = zw + s * 8;
        f2 zp[4];
        #pragma unroll
        for (int j = 0; j < 4; ++j) zp[j] = ((const f2*)zs)[j];
        const float za  = zs[a];
        const float zbv = zs[b];
        const float B4 = zbv * (za * (1.f/24.f) + s1 * (1.f/6.f)) + s2 * 0.5f;
        const float G3 = zbv * (za * (1.f/6.f)  + s1 * 0.5f)      + s2;
        f2 Acp[4];
        #pragma unroll
        for (int i = 0; i < 4; ++i) Acp[i] = B4 * zp[i] + s3p[i];
        #pragma unroll
        for (int c = 0; c < 8; ++c) {
            const float Ac = Acp[c >> 1][c & 1];
            #pragma unroll
            for (int j = 0; j < 4; ++j) s4p[c * 4 + j] += Ac * zp[j];
        }
        #pragma unroll
        for (int i = 0; i < 4; ++i) s3p[i] += G3 * zp[i];
        s2 += zbv * (za * 0.5f + s1);
        s1 += za;
    }

    // ---- publish: S0->sA0, S2->sA2 (A-layout); S1->sB1, S3->sB3 (B-layout);
    //      all L4 -> sT[w] (T-layout) ----
    if ((w & 1) == 0) {
        float* SA = (w == 0) ? sA0 : sA2;
        if (b == 0) SA[a] = s1;
        SA[O2 + l] = s2;
        #pragma unroll
        for (int c = 0; c < 8; ++c) SA[A3IDX(l, c)] = s3p[c >> 1][c & 1];
    } else {
        float* SL = (w == 1) ? sB1 : sB3;
        if (b == 0) SL[a] = s1;
        SL[O2 + l] = s2;
        *(float4*)&SL[B3IDX(a, b, 0)] = make_float4(s3p[0][0], s3p[0][1], s3p[1][0], s3p[1][1]);
        *(float4*)&SL[B3IDX(a, b, 4)] = make_float4(s3p[2][0], s3p[2][1], s3p[3][0], s3p[3][1]);
    }
    #pragma unroll
    for (int i = 0; i < 16; ++i)
        sT[w][i * 64 + l] = make_float4(s4p[2*i][0], s4p[2*i][1], s4p[2*i+1][0], s4p[2*i+1][1]);
    __syncthreads();

    // ---- level 1: half 0 -> P01 = S0 x S1, half 1 -> P23 = S2 x S3 ----
    {
        const int h  = tid >> 7;
        const int ht = tid & 127;
        const int hi = ht >> 6;
        const int la = (ht >> 3) & 7, lb = ht & 7;
        const float* SA  = h ? sA2 : sA0;
        const float* SBb = h ? sB3 : sB1;
        float4* TA = sT[h ? 2 : 0];          // in-place: becomes P.L4
        const float4* TB = sT[h ? 3 : 1];
        const int dh = hi * 4;
        const float A1  = SA[la];
        const float A2v = SA[O2 + la * 8 + lb];
        f2 b1p[2];
        *(float4*)&b1p[0] = *(const float4*)(SBb + dh);
        #pragma unroll
        for (int k = 0; k < 8; ++k) {        // k = c index
            const int f = k * 128 + ht;
            const float A3c = SA[A3IDX(la * 8 + lb, k)];
            f2 b2p[2], b3p[2];
            *(float4*)&b2p[0] = *(const float4*)(SBb + O2 + k * 8 + dh);
            *(float4*)&b3p[0] = *(const float4*)(SBb + B3IDX(lb, k, dh));
            float4 av = TA[f], bv = TB[f];
            f2 r0 = mkf2(av.x, av.y) + mkf2(bv.x, bv.y)
                  + A3c * b1p[0] + A2v * b2p[0] + A1 * b3p[0];
            f2 r1 = mkf2(av.z, av.w) + mkf2(bv.z, bv.w)
                  + A3c * b1p[1] + A2v * b2p[1] + A1 * b3p[1];
            TA[f] = make_float4(r0[0], r0[1], r1[0], r1[1]);
        }
        // L123 of the half's product: P01 -> sPA (A-layout), P23 -> sPB (B-layout)
        float* OP = h ? sPB : sPA;
        const int f3 = ht * 4;
        const int pp = f3 >> 6, qq = (f3 >> 3) & 7, rr = f3 & 7;   // rr in {0,4}
        const float A1p  = SA[pp];
        const float A2pq = SA[O2 + pp * 8 + qq];
        f2 bb1[2], bb2[2], bb3[2];
        *(float4*)&bb1[0] = *(const float4*)(SBb + rr);
        *(float4*)&bb2[0] = *(const float4*)(SBb + O2 + qq * 8 + rr);
        *(float4*)&bb3[0] = *(const float4*)(SBb + B3IDX(pp, qq, rr));
        float o[4];
        #pragma unroll
        for (int j = 0; j < 4; ++j)
            o[j] = SA[A3IDX(pp * 8 + qq, rr + j)] + bb3[j >> 1][j & 1]
                 + A2pq * bb1[j >> 1][j & 1] + A1p * bb2[j >> 1][j & 1];
        if (h == 0) {
            #pragma unroll
            for (int j = 0; j < 4; ++j) OP[A3IDX(pp * 8 + qq, rr + j)] = o[j];
        } else {
            *(float4*)&OP[B3IDX(pp, qq, rr)] = make_float4(o[0], o[1], o[2], o[3]);
        }
        if (ht < 64) OP[O2 + ht] = SA[O2 + ht] + SBb[O2 + ht] + SA[ht >> 3] * SBb[ht & 7];
        if (ht < 8)  OP[ht] = SA[ht] + SBb[ht];
    }
    __syncthreads();

    // ---- level 2: P = P01 x P23; every element stored by its computer ----
    {
        const int c0 = 2 * w;
        f2 a4[8], b4[8];
        #pragma unroll
        for (int k = 0; k < 4; ++k) {
            float4 v = sT[0][(w * 4 + k) * 64 + l];
            a4[2*k] = mkf2(v.x, v.y); a4[2*k+1] = mkf2(v.z, v.w);
            float4 u = sT[2][(w * 4 + k) * 64 + l];
            b4[2*k] = mkf2(u.x, u.y); b4[2*k+1] = mkf2(u.z, u.w);
        }
        const float A1  = sPA[a];
        const float A2v = sPA[O2 + a * 8 + b];
        const float A3_0 = sPA[A3IDX(a * 8 + b, c0)];
        const float A3_1 = sPA[A3IDX(a * 8 + b, c0 + 1)];
        f2 b1p[4], b2p[8], b3p[8];
        *(float4*)&b1p[0] = *(const float4*)(sPB);
        *(float4*)&b1p[2] = *(const float4*)(sPB + 4);
        #pragma unroll
        for (int i = 0; i < 4; ++i) {
            *(float4*)&b2p[2*i] = *(const float4*)(sPB + O2 + c0 * 8 + 4 * i);
            *(float4*)&b3p[2*i] = *(const float4*)(sPB + B3IDX(b, c0, 0) + 4 * i);
        }
        #pragma unroll
        for (int cc = 0; cc < 2; ++cc) {
            const float A3c = cc ? A3_1 : A3_0;
            #pragma unroll
            for (int j = 0; j < 4; ++j)
                a4[cc*4+j] += b4[cc*4+j] + A3c * b1p[j]
                            + A2v * b2p[cc*4+j] + A1 * b3p[cc*4+j];
        }

        float* dst = ws + (size_t)blockIdx.x * SIG;
        float4* dT = (float4*)(dst + O4);
        #pragma unroll
        for (int k = 0; k < 4; ++k)
            dT[(w * 4 + k) * 64 + l] =
                make_float4(a4[2*k][0], a4[2*k][1], a4[2*k+1][0], a4[2*k+1][1]);
        const int pp = f0 >> 6, qq = (f0 >> 3) & 7, rr = f0 & 7;
        const float A1p  = sPA[pp];
        const float A2pq = sPA[O2 + pp * 8 + qq];
        dst[O3 + f0]     = sPA[A3IDX(pp*8+qq, rr)]     + sPB[B3IDX(pp, qq, rr)]
                         + A2pq * sPB[rr]     + A1p * sPB[O2 + qq * 8 + rr];
        dst[O3 + f0 + 1] = sPA[A3IDX(pp*8+qq, rr + 1)] + sPB[B3IDX(pp, qq, rr + 1)]
                         + A2pq * sPB[rr + 1] + A1p * sPB[O2 + qq * 8 + rr + 1];
        if (tid < 64) dst[O2 + tid] = sPA[O2 + tid] + sPB[O2 + tid] + sPA[tid >> 3] * sPB[tid & 7];
        if (tid < 8)  dst[tid] = sPA[tid] + sPB[tid];
    }
}

// ---------------------------------------------------------------------------
// k2: 256 blocks x 256 thr = (batch n, c-quadrant w4). Tree-combine 4 partials.
// ---------------------------------------------------------------------------
__global__ __launch_bounds__(256) void k2_final(const float* __restrict__ ws,
                                                float* __restrict__ out)
{
    __shared__ __align__(16) float sA0[SB], sB1[SB], sA2[SB], sB3[SB];
    __shared__ __align__(16) float sPA[SB], sPB[SB];

    const int tid = threadIdx.x;
    const int n  = blockIdx.x >> 2;
    const int w4 = blockIdx.x & 3;
    const int a = tid >> 5, b = (tid >> 2) & 7, q = tid & 3;
    const int cc = q >> 1, dh4 = q & 1;
    const int c  = 2 * w4 + cc;
    const int dh = dh4 * 4;
    const int f0 = 2 * tid;
    const float* base = ws + (size_t)n * 4 * SIG;
    const float* s0 = base;
    const float* s1g = base + SIG;
    const float* s2g = base + 2 * SIG;
    const float* s3g = base + 3 * SIG;

    // own L4 quadrant f4 of each sig FIRST (latency overlaps staging)
    const int ti = (w4 * 4 + cc * 2 + dh4) * 64 + (a * 8 + b);
    f2 r0[2], r1[2], r2[2], r3[2];
    {
        float4 u0 = ((const float4*)(s0 + O4))[ti];
        r0[0] = mkf2(u0.x, u0.y); r0[1] = mkf2(u0.z, u0.w);
        float4 u1 = ((const float4*)(s1g + O4))[ti];
        r1[0] = mkf2(u1.x, u1.y); r1[1] = mkf2(u1.z, u1.w);
        float4 u2 = ((const float4*)(s2g + O4))[ti];
        r2[0] = mkf2(u2.x, u2.y); r2[1] = mkf2(u2.z, u2.w);
        float4 u3 = ((const float4*)(s3g + O4))[ti];
        r3[0] = mkf2(u3.x, u3.y); r3[1] = mkf2(u3.z, u3.w);
    }

    // stage: S0,S2 -> A-layout; S1,S3 -> B-layout
    if (tid < O3) { sA0[tid] = s0[tid]; sA2[tid] = s2g[tid]; }
    sA0[A3IDX(f0 >> 3, f0 & 7)]       = s0[O3 + f0];
    sA0[A3IDX(f0 >> 3, (f0 & 7) + 1)] = s0[O3 + f0 + 1];
    sA2[A3IDX(f0 >> 3, f0 & 7)]       = s2g[O3 + f0];
    sA2[A3IDX(f0 >> 3, (f0 & 7) + 1)] = s2g[O3 + f0 + 1];
    if (tid < 146) {
        int d4 = (tid < 18) ? tid : 18 + ((tid - 18) >> 4) * 18 + ((tid - 18) & 15);
        ((float4*)sB1)[d4] = ((const float4*)s1g)[tid];
        ((float4*)sB3)[d4] = ((const float4*)s3g)[tid];
    }
    __syncthreads();

    // ---- level 1: L4 slices per-thread; L123 by half-blocks ----
    f2 p01[2], p23[2];
    {
        const float A1a = sA0[a], A2a = sA0[O2 + a * 8 + b];
        const float A3a = sA0[A3IDX(a * 8 + b, c)];
        f2 b1p[2], b2p[2], b3p[2];
        *(float4*)&b1p[0] = *(const float4*)(sB1 + dh);
        *(float4*)&b2p[0] = *(const float4*)(sB1 + O2 + c * 8 + dh);
        *(float4*)&b3p[0] = *(const float4*)(sB1 + B3IDX(b, c, dh));
        #pragma unroll
        for (int j = 0; j < 2; ++j)
            p01[j] = r0[j] + r1[j] + A3a * b1p[j] + A2a * b2p[j] + A1a * b3p[j];
        const float A1b = sA2[a], A2b = sA2[O2 + a * 8 + b];
        const float A3b = sA2[A3IDX(a * 8 + b, c)];
        f2 c1p[2], c2p[2], c3p[2];
        *(float4*)&c1p[0] = *(const float4*)(sB3 + dh);
        *(float4*)&c2p[0] = *(const float4*)(sB3 + O2 + c * 8 + dh);
        *(float4*)&c3p[0] = *(const float4*)(sB3 + B3IDX(b, c, dh));
        #pragma unroll
        for (int j = 0; j < 2; ++j)
            p23[j] = r2[j] + r3[j] + A3b * c1p[j] + A2b * c2p[j] + A1b * c3p[j];

        const int h  = tid >> 7;
        const int ht = tid & 127;
        const float* SA  = h ? sA2 : sA0;
        const float* SBb = h ? sB3 : sB1;
        float* OP = h ? sPB : sPA;
        const int f3 = ht * 4;
        const int pp = f3 >> 6, qq = (f3 >> 3) & 7, rr = f3 & 7;
        const float A1p  = SA[pp];
        const float A2pq = SA[O2 + pp * 8 + qq];
        f2 bb1[2], bb2[2], bb3[2];
        *(float4*)&bb1[0] = *(const float4*)(SBb + rr);
        *(float4*)&bb2[0] = *(const float4*)(SBb + O2 + qq * 8 + rr);
        *(float4*)&bb3[0] = *(const float4*)(SBb + B3IDX(pp, qq, rr));
        float o[4];
        #pragma unroll
        for (int j = 0; j < 4; ++j)
            o[j] = SA[A3IDX(pp * 8 + qq, rr + j)] + bb3[j >> 1][j & 1]
                 + A2pq * bb1[j >> 1][j & 1] + A1p * bb2[j >> 1][j & 1];
        if (h == 0) {
            #pragma unroll
            for (int j = 0; j < 4; ++j) OP[A3IDX(pp * 8 + qq, rr + j)] = o[j];
        } else {
            *(float4*)&OP[B3IDX(pp, qq, rr)] = make_float4(o[0], o[1], o[2], o[3]);
        }
        if (ht < 64) OP[O2 + ht] = SA[O2 + ht] + SBb[O2 + ht] + SA[ht >> 3] * SBb[ht & 7];
        if (ht < 8)  OP[ht] = SA[ht] + SBb[ht];
    }
    __syncthreads();

    // ---- level 2: final = P01 x P23 ----
    float* dst = out + (size_t)n * SIG;
    {
        const float A1  = sPA[a];
        const float A2v = sPA[O2 + a * 8 + b];
        const float A3c = sPA[A3IDX(a * 8 + b, c)];
        f2 b1p[2], b2p[2], b3p[2];
        *(float4*)&b1p[0] = *(const float4*)(sPB + dh);
        *(float4*)&b2p[0] = *(const float4*)(sPB + O2 + c * 8 + dh);
        *(float4*)&b3p[0] = *(const float4*)(sPB + B3IDX(b, c, dh));
        f2 rf[2];
        #pragma unroll
        for (int j = 0; j < 2; ++j)
            rf[j] = p01[j] + p23[j] + A3c * b1p[j] + A2v * b2p[j] + A1 * b3p[j];
        ((float4*)(dst + O4))[((a * 8 + b) * 8 + c) * 2 + dh4] =
            make_float4(rf[0][0], rf[0][1], rf[1][0], rf[1][1]);
    }
    if (w4 == 0) {   // L123 identical across quadrant blocks; store once
        const int pp = f0 >> 6, qq = (f0 >> 3) & 7, rr = f0 & 7;
        const float A1p  = sPA[pp];
        const float A2pq = sPA[O2 + pp * 8 + qq];
        dst[O3 + f0]     = sPA[A3IDX(pp*8+qq, rr)]     + sPB[B3IDX(pp, qq, rr)]
                         + A2pq * sPB[rr]     + A1p * sPB[O2 + qq * 8 + rr];
        dst[O3 + f0 + 1] = sPA[A3IDX(pp*8+qq, rr + 1)] + sPB[B3IDX(pp, qq, rr + 1)]
                         + A2pq * sPB[rr + 1] + A1p * sPB[O2 + qq * 8 + rr + 1];
        if (tid < 64) dst[O2 + tid] = sPA[O2 + tid] + sPB[O2 + tid] + sPA[tid >> 3] * sPB[tid & 7];
        if (tid < 8)  dst[tid] = sPA[tid] + sPB[tid];
    }
}

extern "C" void kernel_launch(void* const* d_in, const int* in_sizes, int n_in,
                              void* d_out, int out_size, void* d_ws, size_t ws_size,
                              hipStream_t stream) {
    const float* path = (const float*)d_in[0];
    float* out = (float*)d_out;
    float* ws  = (float*)d_ws;   // 256 * 4680 * 4 B = 4.79 MB used

    k1_sig<<<NB * 4, 256, 0, stream>>>(path, ws);
    k2_final<<<NB * 4, 256, 0, stream>>>(ws, out);
}